// Round 1
// baseline (2119.874 us; speedup 1.0000x reference)
//
#include <hip/hip_runtime.h>
#include <math.h>

// Problem constants (from reference)
#define NRAYS        32768
#define HID          64
#define MARCH_ITERS  64
#define EPS_         1e-4f
#define NEAR_        0.0f
#define FAR_         1.0f
// step = (T_FAR + 1/TPUT_B) / TPUT_B
#define STEP_        ((1.0f + 1.0f/64.0f) / 64.0f)

// ---------------------------------------------------------------------------
// Prep: transpose W1 (64x64, row-major [k][j]) -> W1T [j][k] in workspace so
// the per-j inner loop reads 64 contiguous floats (4x s_load_dwordx16).
// ---------------------------------------------------------------------------
__global__ void w1_transpose_k(const float* __restrict__ W1,
                               float* __restrict__ W1T) {
    int idx = blockIdx.x * 256 + threadIdx.x;
    if (idx < 64 * 64) {
        int k = idx >> 6;
        int j = idx & 63;
        W1T[j * 64 + k] = W1[k * 64 + j];
    }
}

__device__ __forceinline__ float relu_(float x) { return x > 0.f ? x : 0.f; }

// sdf(p) = W2 . relu(W1 . relu(W0.p + b0) + b1) + b2
// Layer 1+2 fused: only h0[64] is live (keeps VGPRs ~100, no h1 array).
// All weight reads are wave-uniform -> scalar loads (s_load) via K$.
__device__ __forceinline__ float sdf_eval(
    float px, float py, float pz,
    const float* __restrict__ W0, const float* __restrict__ b0,
    const float* __restrict__ W1T, const float* __restrict__ b1,
    const float* __restrict__ W2, float b2s)
{
    float h0[HID];
    #pragma unroll
    for (int j = 0; j < HID; ++j) {
        float a = b0[j] + px * W0[j] + py * W0[64 + j] + pz * W0[128 + j];
        h0[j] = relu_(a);
    }
    float d = b2s;
    // unroll-4 on j: 4 independent 4-way-split dot chains -> 16 concurrent
    // FMA chains, enough to hide v_fma latency; body ~small enough for I$.
    #pragma unroll 4
    for (int j = 0; j < HID; ++j) {
        const float* __restrict__ w = W1T + j * 64;
        float a0 = 0.f, a1 = 0.f, a2 = 0.f, a3 = 0.f;
        #pragma unroll
        for (int k = 0; k < HID; k += 4) {
            a0 += h0[k + 0] * w[k + 0];
            a1 += h0[k + 1] * w[k + 1];
            a2 += h0[k + 2] * w[k + 2];
            a3 += h0[k + 3] * w[k + 3];
        }
        float a = b1[j] + ((a0 + a1) + (a2 + a3));
        d += relu_(a) * W2[j];
    }
    return d;
}

__global__ __launch_bounds__(64) void sdf_march_k(
    const float* __restrict__ rays,
    const float* __restrict__ W0,  const float* __restrict__ b0,
    const float* __restrict__ W1T, const float* __restrict__ b1,
    const float* __restrict__ W2,  const float* __restrict__ b2,
    const float* __restrict__ Wr0, const float* __restrict__ br0,
    const float* __restrict__ Wr1, const float* __restrict__ br1,
    float* __restrict__ out)
{
    const int ray = blockIdx.x * 64 + threadIdx.x;
    const float* rp = rays + ray * 6;
    const float ox = rp[0], oy = rp[1], oz = rp[2];
    const float dx = rp[3], dy = rp[4], dz = rp[5];
    const float b2s = b2[0];

    // ---- sphere-march: 64 sequential sdf evals -------------------------
    bool  hit = false;
    float cd  = NEAR_;
    for (int it = 0; it < MARCH_ITERS; ++it) {
        float d = sdf_eval(ox + dx * cd, oy + dy * cd, oz + dz * cd,
                           W0, b0, W1T, b1, W2, b2s);
        // reference: hits |= (d<EPS)&(cd>=NEAR)&(cd<=FAR);  then
        //            cd = where(~hits, cd+d, cd)   (uses UPDATED hits)
        bool c = (d < EPS_) && (cd >= NEAR_) && (cd <= FAR_);
        hit = hit || c;
        if (!hit) cd += d;
    }

    // ---- reflection net at pts = ro + rd*t, gated by hit ---------------
    const float px = ox + dx * cd, py = oy + dy * cd, pz = oz + dz * cd;
    float r0 = br1[0], r1 = br1[1], r2 = br1[2];
    #pragma unroll 8
    for (int j = 0; j < HID; ++j) {
        float a = br0[j]
                + px * Wr0[j]        + py * Wr0[64 + j]  + pz * Wr0[128 + j]
                + dx * Wr0[192 + j]  + dy * Wr0[256 + j] + dz * Wr0[320 + j];
        a = relu_(a);
        r0 += a * Wr1[j * 3 + 0];
        r1 += a * Wr1[j * 3 + 1];
        r2 += a * Wr1[j * 3 + 2];
    }
    r0 = 1.f / (1.f + expf(-r0));
    r1 = 1.f / (1.f + expf(-r1));
    r2 = 1.f / (1.f + expf(-r2));
    if (!hit) { r0 = 0.f; r1 = 0.f; r2 = 0.f; }

    // ---- tput scan: 65 independent sdf evals; argmin's sd == running min,
    // and tput = sdf(best_pos) == final cm, so idxs/final eval are skipped.
    float cm = sdf_eval(ox, oy, oz, W0, b0, W1T, b1, W2, b2s);
    for (int i = 0; i < 64; ++i) {
        float t_i = STEP_ * (float)(i + 1);
        float sd = sdf_eval(ox + dx * t_i, oy + dy * t_i, oz + dz * t_i,
                            W0, b0, W1T, b1, W2, b2s);
        cm = fminf(cm, sd);
    }

    // ---- store (coalesced float4) --------------------------------------
    reinterpret_cast<float4*>(out)[ray] = make_float4(r0, r1, r2, cm);
}

extern "C" void kernel_launch(void* const* d_in, const int* in_sizes, int n_in,
                              void* d_out, int out_size, void* d_ws, size_t ws_size,
                              hipStream_t stream) {
    const float* rays = (const float*)d_in[0];
    const float* W0   = (const float*)d_in[1];
    const float* b0   = (const float*)d_in[2];
    const float* W1   = (const float*)d_in[3];
    const float* b1   = (const float*)d_in[4];
    const float* W2   = (const float*)d_in[5];
    const float* b2   = (const float*)d_in[6];
    const float* Wr0  = (const float*)d_in[7];
    const float* br0  = (const float*)d_in[8];
    const float* Wr1  = (const float*)d_in[9];
    const float* br1  = (const float*)d_in[10];
    float* out = (float*)d_out;
    float* W1T = (float*)d_ws;   // 64*64*4 = 16 KB scratch

    hipLaunchKernelGGL(w1_transpose_k, dim3(16), dim3(256), 0, stream, W1, W1T);
    // 64-thread blocks: 512 blocks spread over 256 CUs (thread-per-ray).
    hipLaunchKernelGGL(sdf_march_k, dim3(NRAYS / 64), dim3(64), 0, stream,
                       rays, W0, b0, W1T, b1, W2, b2, Wr0, br0, Wr1, br1, out);
}

// Round 2
// 944.275 us; speedup vs baseline: 2.2450x; 2.2450x over previous
//
#include <hip/hip_runtime.h>
#include <math.h>

// Problem constants (from reference)
#define NRAYS        32768
#define HID          64
#define MARCH_ITERS  64
#define EPS_         1e-4f
// step = (T_FAR + 1/TPUT_B) / TPUT_B
#define STEP_        ((1.0f + 1.0f/64.0f) / 64.0f)

// Broadcast lane k's value to all lanes via v_readlane (VALU pipe, result is
// wave-uniform -> lives in an SGPR -> v_fmac v, s, v in the inner loop).
__device__ __forceinline__ float bcast_lane(float x, int k) {
    return __int_as_float(__builtin_amdgcn_readlane(__float_as_int(x), k));
}

// Full-wave butterfly sum: 6 x (ds_swizzle + v_add). All lanes end with the
// bit-identical total (same association tree), so wave-uniform control flow
// on the result is safe.
__device__ __forceinline__ float wave_sum(float x) {
    #pragma unroll
    for (int m = 32; m >= 1; m >>= 1) x += __shfl_xor(x, m, 64);
    return x;
}

// One wave per ray. Lane j owns column j of every MLP layer, pinned in VGPRs
// for the whole kernel: inner loop is pure VALU (readlane + fmac), no loads.
__global__ __launch_bounds__(256, 4) void sdf_wave_k(
    const float* __restrict__ rays,
    const float* __restrict__ W0,  const float* __restrict__ b0,
    const float* __restrict__ W1,  const float* __restrict__ b1,
    const float* __restrict__ W2,  const float* __restrict__ b2,
    const float* __restrict__ Wr0, const float* __restrict__ br0,
    const float* __restrict__ Wr1, const float* __restrict__ br1,
    float* __restrict__ out)
{
    const int wave = threadIdx.x >> 6;            // 4 waves / block
    const int lane = threadIdx.x & 63;
    const int ray  = blockIdx.x * 4 + wave;

    // Wave-uniform ray data (same-address loads broadcast).
    const float* rp = rays + ray * 6;
    const float ox = rp[0], oy = rp[1], oz = rp[2];
    const float dx = rp[3], dy = rp[4], dz = rp[5];

    // ---- pin SDF weights in per-lane registers -------------------------
    const float w0x = W0[lane], w0y = W0[64 + lane], w0z = W0[128 + lane];
    const float b0j = b0[lane];
    float w1[HID];                                 // W1[:, lane] -> 64 VGPRs
    #pragma unroll
    for (int k = 0; k < HID; ++k) w1[k] = W1[k * 64 + lane];   // coalesced per k
    const float b1j = b1[lane];
    const float w2j = W2[lane];
    const float b2s = b2[0];

    // ---- whole-wave SDF eval -------------------------------------------
    auto sdf = [&](float px, float py, float pz) -> float {
        // layer 1: lane j computes h0[j]
        float h = fmaxf(b0j + px * w0x + py * w0y + pz * w0z, 0.f);
        // layer 2: lane j accumulates h1[j] = sum_k h0[k] * W1[k][j]
        float a0 = 0.f, a1 = 0.f, a2 = 0.f, a3 = 0.f;
        #pragma unroll
        for (int k = 0; k < HID; k += 4) {
            a0 += bcast_lane(h, k + 0) * w1[k + 0];
            a1 += bcast_lane(h, k + 1) * w1[k + 1];
            a2 += bcast_lane(h, k + 2) * w1[k + 2];
            a3 += bcast_lane(h, k + 3) * w1[k + 3];
        }
        // output layer: d = b2 + sum_j relu(h1[j] + b1[j]) * W2[j]
        float t = fmaxf(((a0 + a1) + (a2 + a3)) + b1j, 0.f) * w2j;
        return b2s + wave_sum(t);
    };

    // ---- sphere march: 64 sequential evals (wave-uniform state) --------
    bool  hit = false;
    float cd  = 0.f;
    for (int it = 0; it < MARCH_ITERS; ++it) {
        float d = sdf(ox + dx * cd, oy + dy * cd, oz + dz * cd);
        bool c = (d < EPS_) && (cd >= 0.f) && (cd <= 1.f);
        hit = hit || c;
        if (!hit) cd += d;
    }

    // ---- reflection net at hit point (weights loaded here, short-lived)
    {
        const float px = ox + dx * cd, py = oy + dy * cd, pz = oz + dz * cd;
        float a = br0[lane]
                + px * Wr0[lane]       + py * Wr0[64 + lane]  + pz * Wr0[128 + lane]
                + dx * Wr0[192 + lane] + dy * Wr0[256 + lane] + dz * Wr0[320 + lane];
        a = fmaxf(a, 0.f);
        float r0 = wave_sum(a * Wr1[lane * 3 + 0]) + br1[0];
        float r1 = wave_sum(a * Wr1[lane * 3 + 1]) + br1[1];
        float r2 = wave_sum(a * Wr1[lane * 3 + 2]) + br1[2];
        r0 = 1.f / (1.f + expf(-r0));
        r1 = 1.f / (1.f + expf(-r1));
        r2 = 1.f / (1.f + expf(-r2));
        if (!hit) { r0 = 0.f; r1 = 0.f; r2 = 0.f; }

        // ---- tput scan: 65 independent evals; tput == running min ------
        float cm = sdf(ox, oy, oz);
        for (int i = 1; i <= 64; ++i) {
            float t_i = STEP_ * (float)i;
            cm = fminf(cm, sdf(ox + dx * t_i, oy + dy * t_i, oz + dz * t_i));
        }

        if (lane == 0)
            reinterpret_cast<float4*>(out)[ray] = make_float4(r0, r1, r2, cm);
    }
}

extern "C" void kernel_launch(void* const* d_in, const int* in_sizes, int n_in,
                              void* d_out, int out_size, void* d_ws, size_t ws_size,
                              hipStream_t stream) {
    const float* rays = (const float*)d_in[0];
    const float* W0   = (const float*)d_in[1];
    const float* b0   = (const float*)d_in[2];
    const float* W1   = (const float*)d_in[3];
    const float* b1   = (const float*)d_in[4];
    const float* W2   = (const float*)d_in[5];
    const float* b2   = (const float*)d_in[6];
    const float* Wr0  = (const float*)d_in[7];
    const float* br0  = (const float*)d_in[8];
    const float* Wr1  = (const float*)d_in[9];
    const float* br1  = (const float*)d_in[10];
    float* out = (float*)d_out;

    // 1 wave per ray: 32768 waves, 4 waves (rays) per 256-thread block.
    hipLaunchKernelGGL(sdf_wave_k, dim3(NRAYS / 4), dim3(256), 0, stream,
                       rays, W0, b0, W1, b1, W2, b2, Wr0, br0, Wr1, br1, out);
}

// Round 3
// 250.101 us; speedup vs baseline: 8.4761x; 3.7756x over previous
//
#include <hip/hip_runtime.h>
#include <math.h>

// Problem constants
#define NRAYS        32768
#define MARCH_ITERS  64
#define EPS_         1e-4f
#define STEP_        ((1.0f + 1.0f/64.0f) / 64.0f)   // exact in fp32

typedef __attribute__((ext_vector_type(8)))  short  short8;   // 8 bf16 (A/B frag)
typedef __attribute__((ext_vector_type(4)))  float  float4v;  // C/D frag
typedef __attribute__((ext_vector_type(4)))  unsigned uint4v;

__device__ __forceinline__ short8 mk_frag(unsigned p0, unsigned p1,
                                          unsigned p2, unsigned p3) {
    uint4v v = {p0, p1, p2, p3};
    return __builtin_bit_cast(short8, v);
}

// Pack truncated-bf16 of (a_even, b_odd) into one dword: low16 = a>>16, high16 = b&ffff0000.
__device__ __forceinline__ unsigned pack_hi(unsigned a, unsigned b) {
    return (a >> 16) | (b & 0xFFFF0000u);
}

// Exact 3-way truncation split of fp32 x: x == hi + mid + lo (bit-exact).
// hi/mid/lo are the fp32 values whose bf16 images we pack.
struct Split3 { unsigned h, m, l; };
__device__ __forceinline__ Split3 split3(float x) {
    unsigned xu = __float_as_uint(x);
    float xh = __uint_as_float(xu & 0xFFFF0000u);
    float r  = x - xh;                       // exact
    unsigned ru = __float_as_uint(r);
    float xm = __uint_as_float(ru & 0xFFFF0000u);
    float r2 = r - xm;                       // exact, fits in bf16 exactly
    return { xu, ru, __float_as_uint(r2) };
}

// One wave = 16 rays. mfma_f32_16x16x32_bf16 layouts (learn_hip verified):
//   A[m = lane&15][k = (lane>>4)*8 + j]   (8 bf16 / lane)
//   B[k = (lane>>4)*8 + j][n = lane&15]
//   C/D: col = lane&15, row = (lane>>4)*4 + reg
__global__ __launch_bounds__(256, 2) void sdf_mfma_k(
    const float* __restrict__ rays,
    const float* __restrict__ W0,  const float* __restrict__ b0,
    const float* __restrict__ W1,  const float* __restrict__ b1,
    const float* __restrict__ W2,  const float* __restrict__ b2,
    const float* __restrict__ Wr0, const float* __restrict__ br0,
    const float* __restrict__ Wr1, const float* __restrict__ br1,
    float* __restrict__ out)
{
    const int lane   = threadIdx.x & 63;
    const int waveId = threadIdx.x >> 6;
    const int quad   = lane >> 4;
    const int m      = lane & 15;
    const int rayBase = (blockIdx.x * 4 + waveId) * 16;

    // ---- per-lane ray data (ray = rayBase + m, replicated over 4 quads) ----
    const float* rp = rays + (rayBase + m) * 6;
    const float ox = rp[0], oy = rp[1], oz = rp[2];
    const float dx = rp[3], dy = rp[4], dz = rp[5];

    // ---- W0/b0 for this lane's 16 A-frag k-slots (VGPR-pinned) ----
    float w0x[2][8], w0y[2][8], w0z[2][8], b0r[2][8];
    #pragma unroll
    for (int h = 0; h < 2; ++h)
        #pragma unroll
        for (int j = 0; j < 8; ++j) {
            int k = 32 * h + quad * 8 + j;
            w0x[h][j] = W0[k]; w0y[h][j] = W0[64 + k]; w0z[h][j] = W0[128 + k];
            b0r[h][j] = b0[k];
        }

    // ---- W1 B-fragments, 3-way split, VGPR-pinned (24 frags = 96 VGPRs) ----
    short8 Bh[2][4], Bm[2][4], Bl[2][4];
    #pragma unroll
    for (int h = 0; h < 2; ++h)
        #pragma unroll
        for (int t = 0; t < 4; ++t) {
            unsigned ph[4], pm[4], pl[4];
            #pragma unroll
            for (int jp = 0; jp < 4; ++jp) {
                int k0 = 32 * h + quad * 8 + 2 * jp;
                int n  = 16 * t + m;
                Split3 a = split3(W1[k0 * 64 + n]);
                Split3 b = split3(W1[(k0 + 1) * 64 + n]);
                ph[jp] = pack_hi(a.h, b.h);
                pm[jp] = pack_hi(a.m, b.m);
                pl[jp] = pack_hi(a.l, b.l);
            }
            Bh[h][t] = mk_frag(ph[0], ph[1], ph[2], ph[3]);
            Bm[h][t] = mk_frag(pm[0], pm[1], pm[2], pm[3]);
            Bl[h][t] = mk_frag(pl[0], pl[1], pl[2], pl[3]);
        }

    // ---- b1 / W2 per-lane (col = 16t + m), b2 scalar ----
    float b1t[4], w2t[4];
    #pragma unroll
    for (int t = 0; t < 4; ++t) { b1t[t] = b1[16 * t + m]; w2t[t] = W2[16 * t + m]; }
    const float b2s = b2[0];
    // scatter source: lane holding d[m] after pre-select = 16*(m>>2) + (m&3)
    const int srcLane = ((m >> 2) << 4) | (m & 3);

    // ---- whole-wave batched SDF eval: 16 rays at once ----
    auto evalSDF = [&](float px, float py, float pz) -> float {
        // layer 1 on VALU, directly in A-fragment slots; split to 3x bf16
        short8 Ah[2], Am[2], Al[2];
        #pragma unroll
        for (int h = 0; h < 2; ++h) {
            float hv[8];
            #pragma unroll
            for (int j = 0; j < 8; ++j)
                hv[j] = fmaxf(fmaf(px, w0x[h][j],
                              fmaf(py, w0y[h][j],
                              fmaf(pz, w0z[h][j], b0r[h][j]))), 0.f);
            unsigned ph[4], pm[4], pl[4];
            #pragma unroll
            for (int jp = 0; jp < 4; ++jp) {
                Split3 a = split3(hv[2 * jp]);
                Split3 b = split3(hv[2 * jp + 1]);
                ph[jp] = pack_hi(a.h, b.h);
                pm[jp] = pack_hi(a.m, b.m);
                pl[jp] = pack_hi(a.l, b.l);
            }
            Ah[h] = mk_frag(ph[0], ph[1], ph[2], ph[3]);
            Am[h] = mk_frag(pm[0], pm[1], pm[2], pm[3]);
            Al[h] = mk_frag(pl[0], pl[1], pl[2], pl[3]);
        }

        // layer 2 on MFMA: 6 split-products x 2 K-halves x 4 col-tiles.
        // b1 folded into C-init; small terms accumulated first.
        float4v C[4];
        #pragma unroll
        for (int t = 0; t < 4; ++t) C[t] = (float4v){b1t[t], b1t[t], b1t[t], b1t[t]};
        #pragma unroll
        for (int h = 0; h < 2; ++h) {
            #pragma unroll
            for (int t = 0; t < 4; ++t)
                C[t] = __builtin_amdgcn_mfma_f32_16x16x32_bf16(Am[h], Bm[h][t], C[t], 0, 0, 0);
            #pragma unroll
            for (int t = 0; t < 4; ++t)
                C[t] = __builtin_amdgcn_mfma_f32_16x16x32_bf16(Ah[h], Bl[h][t], C[t], 0, 0, 0);
            #pragma unroll
            for (int t = 0; t < 4; ++t)
                C[t] = __builtin_amdgcn_mfma_f32_16x16x32_bf16(Al[h], Bh[h][t], C[t], 0, 0, 0);
            #pragma unroll
            for (int t = 0; t < 4; ++t)
                C[t] = __builtin_amdgcn_mfma_f32_16x16x32_bf16(Ah[h], Bm[h][t], C[t], 0, 0, 0);
            #pragma unroll
            for (int t = 0; t < 4; ++t)
                C[t] = __builtin_amdgcn_mfma_f32_16x16x32_bf16(Am[h], Bh[h][t], C[t], 0, 0, 0);
            #pragma unroll
            for (int t = 0; t < 4; ++t)
                C[t] = __builtin_amdgcn_mfma_f32_16x16x32_bf16(Ah[h], Bh[h][t], C[t], 0, 0, 0);
        }

        // layer 3: d[row] = b2 + sum_n relu(h1) * W2;  row = quad*4 + r
        float part[4] = {0.f, 0.f, 0.f, 0.f};
        #pragma unroll
        for (int t = 0; t < 4; ++t)
            #pragma unroll
            for (int r = 0; r < 4; ++r)
                part[r] = fmaf(fmaxf(C[t][r], 0.f), w2t[t], part[r]);
        #pragma unroll
        for (int mask = 1; mask < 16; mask <<= 1)
            #pragma unroll
            for (int r = 0; r < 4; ++r)
                part[r] += __shfl_xor(part[r], mask, 64);
        // pre-select own reg (lane&3 == m&3), then fetch d[m] from srcLane
        float sel = (m & 2) ? ((m & 1) ? part[3] : part[2])
                            : ((m & 1) ? part[1] : part[0]);
        return b2s + __shfl(sel, srcLane, 64);
    };

    // ---- sphere march (64 sequential evals) ----
    bool  hit = false;
    float cd  = 0.f;
    for (int it = 0; it < MARCH_ITERS; ++it) {
        float d = evalSDF(fmaf(dx, cd, ox), fmaf(dy, cd, oy), fmaf(dz, cd, oz));
        bool c = (d < EPS_) && (cd >= 0.f) && (cd <= 1.f);
        hit = hit || c;
        if (!hit) cd += d;
        if (__all(hit)) break;   // all 16 rays frozen -> remaining iters are no-ops
    }

    // ---- reflection net (one-time): quad q handles hidden j in [16q,16q+16) ----
    const float px = fmaf(dx, cd, ox), py = fmaf(dy, cd, oy), pz = fmaf(dz, cd, oz);
    float r0 = 0.f, r1 = 0.f, r2 = 0.f;
    #pragma unroll 4
    for (int jj = 0; jj < 16; ++jj) {
        int j = quad * 16 + jj;
        float a = fmaf(px, Wr0[j],
                  fmaf(py, Wr0[64 + j],
                  fmaf(pz, Wr0[128 + j],
                  fmaf(dx, Wr0[192 + j],
                  fmaf(dy, Wr0[256 + j],
                  fmaf(dz, Wr0[320 + j], br0[j]))))));
        a = fmaxf(a, 0.f);
        r0 = fmaf(a, Wr1[j * 3 + 0], r0);
        r1 = fmaf(a, Wr1[j * 3 + 1], r1);
        r2 = fmaf(a, Wr1[j * 3 + 2], r2);
    }
    r0 += __shfl_xor(r0, 16, 64); r0 += __shfl_xor(r0, 32, 64);
    r1 += __shfl_xor(r1, 16, 64); r1 += __shfl_xor(r1, 32, 64);
    r2 += __shfl_xor(r2, 16, 64); r2 += __shfl_xor(r2, 32, 64);
    r0 = 1.f / (1.f + expf(-(r0 + br1[0])));
    r1 = 1.f / (1.f + expf(-(r1 + br1[1])));
    r2 = 1.f / (1.f + expf(-(r2 + br1[2])));
    if (!hit) { r0 = 0.f; r1 = 0.f; r2 = 0.f; }

    // ---- tput scan: 65 independent evals; tput == running min (validated R1/R2) ----
    float cm = evalSDF(ox, oy, oz);
    for (int i = 1; i <= 64; ++i) {
        float t_i = STEP_ * (float)i;
        cm = fminf(cm, evalSDF(fmaf(dx, t_i, ox), fmaf(dy, t_i, oy), fmaf(dz, t_i, oz)));
    }

    if (lane < 16)
        reinterpret_cast<float4*>(out)[rayBase + lane] = make_float4(r0, r1, r2, cm);
}

extern "C" void kernel_launch(void* const* d_in, const int* in_sizes, int n_in,
                              void* d_out, int out_size, void* d_ws, size_t ws_size,
                              hipStream_t stream) {
    const float* rays = (const float*)d_in[0];
    const float* W0   = (const float*)d_in[1];
    const float* b0   = (const float*)d_in[2];
    const float* W1   = (const float*)d_in[3];
    const float* b1   = (const float*)d_in[4];
    const float* W2   = (const float*)d_in[5];
    const float* b2   = (const float*)d_in[6];
    const float* Wr0  = (const float*)d_in[7];
    const float* br0  = (const float*)d_in[8];
    const float* Wr1  = (const float*)d_in[9];
    const float* br1  = (const float*)d_in[10];
    float* out = (float*)d_out;

    // 16 rays/wave, 4 waves/block -> 512 blocks = 2048 waves = 2/SIMD resident.
    hipLaunchKernelGGL(sdf_mfma_k, dim3(NRAYS / 64), dim3(256), 0, stream,
                       rays, W0, b0, W1, b1, W2, b2, Wr0, br0, Wr1, br1, out);
}

// Round 4
// 246.755 us; speedup vs baseline: 8.5910x; 1.0136x over previous
//
#include <hip/hip_runtime.h>
#include <math.h>

// Problem constants
#define NRAYS        32768
#define MARCH_ITERS  64
#define EPS_         1e-4f
#define STEP_        ((1.0f + 1.0f/64.0f) / 64.0f)   // exact in fp32

typedef __attribute__((ext_vector_type(8)))  short    short8;   // 8 bf16
typedef __attribute__((ext_vector_type(4)))  float    float4v;  // C/D frag
typedef __attribute__((ext_vector_type(4)))  unsigned uint4v;

__device__ __forceinline__ short8 mk_frag(unsigned p0, unsigned p1,
                                          unsigned p2, unsigned p3) {
    uint4v v = {p0, p1, p2, p3};
    return __builtin_bit_cast(short8, v);
}

// One v_perm_b32: low16 = a.bytes[3:2] (trunc-bf16 of a), high16 = b.bytes[3:2].
__device__ __forceinline__ unsigned packbf(unsigned a, unsigned b) {
    return __builtin_amdgcn_perm(b, a, 0x07060302u);
}

// Exact 3-way truncation split: x == hi + mid + lo bit-exactly in fp32.
struct Split3 { unsigned h, m, l; };
__device__ __forceinline__ Split3 split3(float x) {
    unsigned xu = __float_as_uint(x);
    float xh = __uint_as_float(xu & 0xFFFF0000u);
    float r  = x - xh;                        // exact
    unsigned ru = __float_as_uint(r);
    float xm = __uint_as_float(ru & 0xFFFF0000u);
    float r2 = r - xm;                        // exact, fits bf16
    return { xu, ru, __float_as_uint(r2) };
}

// One wave = 16 rays, mfma_f32_16x16x32_bf16.
//   A[m=lane&15][k=(lane>>4)*8+j]  B[k=(lane>>4)*8+j][n=lane&15]
//   C/D: col=lane&15, row=(lane>>4)*4+reg
// Even blocks: sphere march + reflection net (writes out.xyz).
// Odd  blocks: tput scan, 2-deep pipelined   (writes out.w).
__global__ __launch_bounds__(256, 2) void sdf_split_k(
    const float* __restrict__ rays,
    const float* __restrict__ W0,  const float* __restrict__ b0,
    const float* __restrict__ W1,  const float* __restrict__ b1,
    const float* __restrict__ W2,  const float* __restrict__ b2,
    const float* __restrict__ Wr0, const float* __restrict__ br0,
    const float* __restrict__ Wr1, const float* __restrict__ br1,
    float* __restrict__ out)
{
    const int lane   = threadIdx.x & 63;
    const int waveId = threadIdx.x >> 6;
    const int quad   = lane >> 4;
    const int m      = lane & 15;
    const int kind   = blockIdx.x & 1;                 // 0=march, 1=tput
    const int rayBase = ((blockIdx.x >> 1) * 4 + waveId) * 16;

    // ---- per-lane ray (ray = rayBase + m, replicated over quads) ----
    const float* rp = rays + (rayBase + m) * 6;
    const float ox = rp[0], oy = rp[1], oz = rp[2];
    const float dx = rp[3], dy = rp[4], dz = rp[5];

    // ---- W1 B-fragments, 3-way split, VGPR-pinned (96 VGPRs) ----
    // Bf[0]=hi, Bf[1]=mid, Bf[2]=lo
    short8 Bf[3][2][4];
    #pragma unroll
    for (int h = 0; h < 2; ++h)
        #pragma unroll
        for (int t = 0; t < 4; ++t) {
            unsigned ph[4], pm[4], pl[4];
            #pragma unroll
            for (int jp = 0; jp < 4; ++jp) {
                int k0 = 32 * h + quad * 8 + 2 * jp;
                int n  = 16 * t + m;
                Split3 a = split3(W1[k0 * 64 + n]);
                Split3 b = split3(W1[(k0 + 1) * 64 + n]);
                ph[jp] = packbf(a.h, b.h);
                pm[jp] = packbf(a.m, b.m);
                pl[jp] = packbf(a.l, b.l);
            }
            Bf[0][h][t] = mk_frag(ph[0], ph[1], ph[2], ph[3]);
            Bf[1][h][t] = mk_frag(pm[0], pm[1], pm[2], pm[3]);
            Bf[2][h][t] = mk_frag(pl[0], pl[1], pl[2], pl[3]);
        }

    float b1t[4], w2t[4];
    #pragma unroll
    for (int t = 0; t < 4; ++t) { b1t[t] = b1[16 * t + m]; w2t[t] = W2[16 * t + m]; }
    const float b2s = b2[0];
    const int srcLane = ((m >> 2) << 4) | (m & 3);     // lane holding d[m]

    // ---- layer 1 + split into A-frags: A[0..1]=Ah, A[2..3]=Am, A[4..5]=Al ----
    auto mkA = [&](float px, float py, float pz, short8* A) {
        #pragma unroll
        for (int h = 0; h < 2; ++h) {
            unsigned ph[4], pm[4], pl[4];
            #pragma unroll
            for (int jp = 0; jp < 4; ++jp) {
                int k = 32 * h + quad * 8 + 2 * jp;
                float va = fmaxf(fmaf(px, W0[k],
                             fmaf(py, W0[64 + k],
                             fmaf(pz, W0[128 + k], b0[k]))), 0.f);
                float vb = fmaxf(fmaf(px, W0[k + 1],
                             fmaf(py, W0[64 + k + 1],
                             fmaf(pz, W0[128 + k + 1], b0[k + 1]))), 0.f);
                Split3 a = split3(va);
                Split3 b = split3(vb);
                ph[jp] = packbf(a.h, b.h);
                pm[jp] = packbf(a.m, b.m);
                pl[jp] = packbf(a.l, b.l);
            }
            A[h]     = mk_frag(ph[0], ph[1], ph[2], ph[3]);
            A[2 + h] = mk_frag(pm[0], pm[1], pm[2], pm[3]);
            A[4 + h] = mk_frag(pl[0], pl[1], pl[2], pl[3]);
        }
    };

    // product order (same as R3, small-first): (Am,Bm)(Ah,Bl)(Al,Bh)(Ah,Bm)(Am,Bh)(Ah,Bh)
    const int pa_[6] = {1, 0, 2, 0, 1, 0};   // A split index (0=h,1=m,2=l)
    const int pb_[6] = {1, 2, 0, 1, 0, 0};   // B split index

    auto evalOne = [&](const short8* A) -> float {
        float4v C[4];
        #pragma unroll
        for (int t = 0; t < 4; ++t) C[t] = (float4v){b1t[t], b1t[t], b1t[t], b1t[t]};
        #pragma unroll
        for (int h = 0; h < 2; ++h)
            #pragma unroll
            for (int p = 0; p < 6; ++p)
                #pragma unroll
                for (int t = 0; t < 4; ++t)
                    C[t] = __builtin_amdgcn_mfma_f32_16x16x32_bf16(
                        A[pa_[p] * 2 + h], Bf[pb_[p]][h][t], C[t], 0, 0, 0);
        float part[4] = {0.f, 0.f, 0.f, 0.f};
        #pragma unroll
        for (int t = 0; t < 4; ++t)
            #pragma unroll
            for (int r = 0; r < 4; ++r)
                part[r] = fmaf(fmaxf(C[t][r], 0.f), w2t[t], part[r]);
        #pragma unroll
        for (int mask = 1; mask < 16; mask <<= 1)
            #pragma unroll
            for (int r = 0; r < 4; ++r)
                part[r] += __shfl_xor(part[r], mask, 64);
        float sel = (m & 2) ? ((m & 1) ? part[3] : part[2])
                            : ((m & 1) ? part[1] : part[0]);
        return b2s + __shfl(sel, srcLane, 64);
    };

    // Two evals interleaved: 8 independent MFMA chains + 2 parallel reductions.
    auto evalPair = [&](const short8* Aa, const short8* Ab, float& da, float& db) {
        float4v C[4], D[4];
        #pragma unroll
        for (int t = 0; t < 4; ++t) {
            C[t] = (float4v){b1t[t], b1t[t], b1t[t], b1t[t]};
            D[t] = C[t];
        }
        #pragma unroll
        for (int h = 0; h < 2; ++h)
            #pragma unroll
            for (int p = 0; p < 6; ++p) {
                #pragma unroll
                for (int t = 0; t < 4; ++t)
                    C[t] = __builtin_amdgcn_mfma_f32_16x16x32_bf16(
                        Aa[pa_[p] * 2 + h], Bf[pb_[p]][h][t], C[t], 0, 0, 0);
                #pragma unroll
                for (int t = 0; t < 4; ++t)
                    D[t] = __builtin_amdgcn_mfma_f32_16x16x32_bf16(
                        Ab[pa_[p] * 2 + h], Bf[pb_[p]][h][t], D[t], 0, 0, 0);
            }
        float pa[4] = {0.f, 0.f, 0.f, 0.f}, pb[4] = {0.f, 0.f, 0.f, 0.f};
        #pragma unroll
        for (int t = 0; t < 4; ++t)
            #pragma unroll
            for (int r = 0; r < 4; ++r) {
                pa[r] = fmaf(fmaxf(C[t][r], 0.f), w2t[t], pa[r]);
                pb[r] = fmaf(fmaxf(D[t][r], 0.f), w2t[t], pb[r]);
            }
        #pragma unroll
        for (int mask = 1; mask < 16; mask <<= 1)
            #pragma unroll
            for (int r = 0; r < 4; ++r) {
                pa[r] += __shfl_xor(pa[r], mask, 64);
                pb[r] += __shfl_xor(pb[r], mask, 64);
            }
        float sa = (m & 2) ? ((m & 1) ? pa[3] : pa[2]) : ((m & 1) ? pa[1] : pa[0]);
        float sb = (m & 2) ? ((m & 1) ? pb[3] : pb[2]) : ((m & 1) ? pb[1] : pb[0]);
        da = b2s + __shfl(sa, srcLane, 64);
        db = b2s + __shfl(sb, srcLane, 64);
    };

    if (kind == 0) {
        // ---- sphere march: 64 sequential evals ----
        bool  hit = false;
        float cd  = 0.f;
        #pragma unroll 1
        for (int it = 0; it < MARCH_ITERS; ++it) {
            short8 A[6];
            mkA(fmaf(dx, cd, ox), fmaf(dy, cd, oy), fmaf(dz, cd, oz), A);
            float d = evalOne(A);
            bool c = (d < EPS_) && (cd >= 0.f) && (cd <= 1.f);
            hit = hit || c;
            if (!hit) cd += d;
            if (__all(hit)) break;          // all 16 rays frozen
        }

        // ---- reflection net: quad q handles hidden j in [16q, 16q+16) ----
        const float px = fmaf(dx, cd, ox), py = fmaf(dy, cd, oy), pz = fmaf(dz, cd, oz);
        float r0 = 0.f, r1 = 0.f, r2 = 0.f;
        #pragma unroll 4
        for (int jj = 0; jj < 16; ++jj) {
            int j = quad * 16 + jj;
            float a = fmaf(px, Wr0[j],
                      fmaf(py, Wr0[64 + j],
                      fmaf(pz, Wr0[128 + j],
                      fmaf(dx, Wr0[192 + j],
                      fmaf(dy, Wr0[256 + j],
                      fmaf(dz, Wr0[320 + j], br0[j]))))));
            a = fmaxf(a, 0.f);
            r0 = fmaf(a, Wr1[j * 3 + 0], r0);
            r1 = fmaf(a, Wr1[j * 3 + 1], r1);
            r2 = fmaf(a, Wr1[j * 3 + 2], r2);
        }
        r0 += __shfl_xor(r0, 16, 64); r0 += __shfl_xor(r0, 32, 64);
        r1 += __shfl_xor(r1, 16, 64); r1 += __shfl_xor(r1, 32, 64);
        r2 += __shfl_xor(r2, 16, 64); r2 += __shfl_xor(r2, 32, 64);
        r0 = 1.f / (1.f + expf(-(r0 + br1[0])));
        r1 = 1.f / (1.f + expf(-(r1 + br1[1])));
        r2 = 1.f / (1.f + expf(-(r2 + br1[2])));
        if (!hit) { r0 = 0.f; r1 = 0.f; r2 = 0.f; }
        if (lane < 16) {
            float* op = out + (rayBase + lane) * 4;
            op[0] = r0; op[1] = r1; op[2] = r2;
        }
    } else {
        // ---- tput scan: 65 independent evals, pipelined 2-wide ----
        short8 A0[6], A1[6];
        mkA(ox, oy, oz, A0);
        float cm = evalOne(A0);
        #pragma unroll 1
        for (int i = 1; i <= 63; i += 2) {
            float ta = STEP_ * (float)i;
            float tb = STEP_ * (float)(i + 1);
            mkA(fmaf(dx, ta, ox), fmaf(dy, ta, oy), fmaf(dz, ta, oz), A0);
            mkA(fmaf(dx, tb, ox), fmaf(dy, tb, oy), fmaf(dz, tb, oz), A1);
            float da, db;
            evalPair(A0, A1, da, db);
            cm = fminf(cm, fminf(da, db));   // min associative: pairing exact
        }
        if (lane < 16)
            out[(rayBase + lane) * 4 + 3] = cm;
    }
}

extern "C" void kernel_launch(void* const* d_in, const int* in_sizes, int n_in,
                              void* d_out, int out_size, void* d_ws, size_t ws_size,
                              hipStream_t stream) {
    const float* rays = (const float*)d_in[0];
    const float* W0   = (const float*)d_in[1];
    const float* b0   = (const float*)d_in[2];
    const float* W1   = (const float*)d_in[3];
    const float* b1   = (const float*)d_in[4];
    const float* W2   = (const float*)d_in[5];
    const float* b2   = (const float*)d_in[6];
    const float* Wr0  = (const float*)d_in[7];
    const float* br0  = (const float*)d_in[8];
    const float* Wr1  = (const float*)d_in[9];
    const float* br1  = (const float*)d_in[10];
    float* out = (float*)d_out;

    // 1024 blocks x 4 waves = 4096 waves: even blocks march (out.xyz),
    // odd blocks tput (out.w); 16 rays per wave.
    hipLaunchKernelGGL(sdf_split_k, dim3(NRAYS / 16 / 2), dim3(256), 0, stream,
                       rays, W0, b0, W1, b1, W2, b2, Wr0, br0, Wr1, br1, out);
}